// Round 1
// baseline (211.055 us; speedup 1.0000x reference)
//
#include <hip/hip_runtime.h>

// NALU: B=1024, I=512, O=512
//   w1 = tanh(w_hat)*sigmoid(m_hat)                 [I,O]
//   a  = x @ w1                                     [B,O]
//   m1 = exp(min(log(max(|x|,eps)) @ w1, 20))       [B,O]
//   ms = prod_i ( sign(x)*|w1^T| + (1-|w1^T|) )     [B,O]  (I==O => ws_oi[o][i] = |w1[o*O+i]|)
//   out = g1*a + (1-g1)*m1*clip(ms,-1,1),  g1 = sigmoid(g)
//
// Identity used for ms: sign=+1 -> term==1 exactly; sign=-1 -> term = 1-2w.
// So ms = prod over negative-x positions of (1 + tm1[i][o]), tm1 = -2|w1^T|.
// Implemented as pp = fma(pp, u, pp) with u = and(tm1, signmask(x)) -> 2 VALU/elem.

#define B_N 1024
#define I_N 512
#define O_N 512

// ---- prep: w1 (natural layout) + tm1 = transpose(-2|w1|) via LDS tile ----
__global__ __launch_bounds__(256) void prep_w_kernel(const float* __restrict__ wh,
                                                     const float* __restrict__ mh,
                                                     float* __restrict__ w1,
                                                     float* __restrict__ tm1) {
    __shared__ float tile[32][33];            // +1 pad: conflict-free transpose
    const int bx = blockIdx.x, by = blockIdx.y;
    const int tx = threadIdx.x & 31;
    const int ty = threadIdx.x >> 5;          // 0..7
#pragma unroll
    for (int r = 0; r < 32; r += 8) {
        const int row = by * 32 + ty + r;     // i index of w1 [I,O]
        const int col = bx * 32 + tx;         // o index
        const int k = row * O_N + col;
        const float w = tanhf(wh[k]) * (1.0f / (1.0f + expf(-mh[k])));
        w1[k] = w;
        tile[ty + r][tx] = -2.0f * fabsf(w);
    }
    __syncthreads();
    // tm1[p][q] = -2|w1[q][p]| : p = bx*32 + c, q = by*32 + r_tile
#pragma unroll
    for (int r = 0; r < 32; r += 8) {
        const int orow = bx * 32 + ty + r;
        const int ocol = by * 32 + tx;
        tm1[orow * O_N + ocol] = tile[tx][ty + r];
    }
}

// ---- prep: pack (x, log(max(|x|,eps))) as float2 for uniform s_load in main ----
__global__ __launch_bounds__(256) void prep_x_kernel(const float* __restrict__ x,
                                                     float2* __restrict__ xl) {
    const int k = blockIdx.x * 256 + threadIdx.x;
    const float xv = x[k];
    const float lx = logf(fmaxf(fabsf(xv), 1e-7f));
    xl[k] = make_float2(xv, lx);
}

// ---- main: per thread one o, 8 b-rows; 512-deep i loop ----
// grid (2, 128): blockIdx.x = o-tile of 256, blockIdx.y = b-group of 8.
__global__ __launch_bounds__(256) void nalu_main_kernel(const float* __restrict__ w1,
                                                        const float* __restrict__ tm1,
                                                        const float4* __restrict__ xl4,
                                                        const float* __restrict__ g,
                                                        float* __restrict__ out) {
    const int o  = blockIdx.x * 256 + threadIdx.x;
    const int b0 = blockIdx.y * 8;

    float aa[8], ss[8], pp[8];
#pragma unroll
    for (int r = 0; r < 8; ++r) { aa[r] = 0.0f; ss[r] = 0.0f; pp[r] = 1.0f; }

#pragma unroll 2
    for (int i = 0; i < I_N; i += 2) {
        const float w0 = w1[i * O_N + o];
        const float w1v = w1[(i + 1) * O_N + o];
        const float t0 = tm1[i * O_N + o];
        const float t1 = tm1[(i + 1) * O_N + o];
#pragma unroll
        for (int r = 0; r < 8; ++r) {
            // uniform address -> scalar s_load_dwordx4: (x_i, lx_i, x_{i+1}, lx_{i+1})
            const float4 q = xl4[(b0 + r) * (I_N / 2) + (i >> 1)];
            aa[r] = fmaf(q.x, w0, aa[r]);
            ss[r] = fmaf(q.y, w0, ss[r]);
            const int m0 = __float_as_int(q.x) >> 31;           // scalar: 0 or -1
            const float u0 = __int_as_float(__float_as_int(t0) & m0);
            pp[r] = fmaf(pp[r], u0, pp[r]);                     // pp *= (1+u0)
            aa[r] = fmaf(q.z, w1v, aa[r]);
            ss[r] = fmaf(q.w, w1v, ss[r]);
            const int m1m = __float_as_int(q.z) >> 31;
            const float u1 = __int_as_float(__float_as_int(t1) & m1m);
            pp[r] = fmaf(pp[r], u1, pp[r]);
        }
    }

    const float g1 = 1.0f / (1.0f + expf(-g[o]));
    const float omg = 1.0f - g1;
#pragma unroll
    for (int r = 0; r < 8; ++r) {
        const float m1v = expf(fminf(ss[r], 20.0f));
        const float msv = fminf(fmaxf(pp[r], -1.0f), 1.0f);
        out[(b0 + r) * O_N + o] = g1 * aa[r] + omg * m1v * msv;
    }
}

extern "C" void kernel_launch(void* const* d_in, const int* in_sizes, int n_in,
                              void* d_out, int out_size, void* d_ws, size_t ws_size,
                              hipStream_t stream) {
    const float* x  = (const float*)d_in[0];   // [B, I]
    const float* wh = (const float*)d_in[1];   // [I, O]
    const float* mh = (const float*)d_in[2];   // [I, O]
    const float* g  = (const float*)d_in[3];   // [O]
    float* out = (float*)d_out;                // [B, O] fp32

    char* ws = (char*)d_ws;
    float*  w1  = (float*)ws;                   // 1 MB  [I,O]
    float*  tm1 = (float*)(ws + (1u << 20));    // 1 MB  [I,O] (transposed -2|w1|)
    float2* xl  = (float2*)(ws + (2u << 20));   // 4 MB  [B,I] packed (x, log|x|)

    prep_w_kernel<<<dim3(16, 16), 256, 0, stream>>>(wh, mh, w1, tm1);
    prep_x_kernel<<<(B_N * I_N) / 256, 256, 0, stream>>>(x, xl);
    nalu_main_kernel<<<dim3(2, 128), 256, 0, stream>>>(w1, tm1, (const float4*)xl, g, out);
}

// Round 2
// 108.868 us; speedup vs baseline: 1.9386x; 1.9386x over previous
//
#include <hip/hip_runtime.h>

// NALU: B=1024, I=512, O=512, fp32.
//   w1 = tanh(w_hat)*sigmoid(m_hat)                 [I,O]
//   a  = x @ w1                                     [B,O]
//   s  = log(max(|x|,eps)) @ w1;  m1 = exp(min(s,20))
//   ms = prod_i sign-terms  -> |term| path
//   out = g1*a + (1-g1)*m1*clip(ms,-1,1)
//
// Numerics: s ~ N(-143, 11^2) for these inputs => m1 <= ~2e-37 everywhere,
// so the (1-g1)*m1*clip(ms) term is < 1e-36 in absolute value -- invisible at
// fp32 output scale (threshold 0.555). We therefore skip the O(B*O*I) ms
// product on the fast path, GUARDED exactly: any element with s > -80 takes a
// cold path that computes the true ms product (so correctness never depends
// on the distribution argument).

#define B_N 1024
#define I_N 512
#define O_N 512

// ---- fused prep: w1 = tanh*sigmoid (1 MB) and packed (x, log|x|) (4 MB) ----
// grid covers I*O elements for w1 then B*I elements for xl.
__global__ __launch_bounds__(256) void prep_kernel(const float* __restrict__ x,
                                                   const float* __restrict__ wh,
                                                   const float* __restrict__ mh,
                                                   float* __restrict__ w1,
                                                   float2* __restrict__ xl) {
    const int idx = blockIdx.x * 256 + threadIdx.x;
    if (idx < I_N * O_N) {
        const float w = tanhf(wh[idx]) * (1.0f / (1.0f + expf(-mh[idx])));
        w1[idx] = w;
    } else {
        const int xi = idx - I_N * O_N;   // < B_N*I_N by grid sizing
        const float xv = x[xi];
        xl[xi] = make_float2(xv, logf(fmaxf(fabsf(xv), 1e-7f)));
    }
}

// ---- main: block = 512 threads (8 waves). o = bx*256 + (tid&255).
// Wave-half (tid>>8, wave-uniform) picks 4 of the block's 8 b-rows.
// x/lx fetched at wave-uniform addresses -> scalar s_load (proven R1: SGPR=112).
__global__ __launch_bounds__(512, 2) void nalu_main_kernel(const float* __restrict__ w1,
                                                           const float4* __restrict__ xl4,
                                                           const float* __restrict__ x,
                                                           const float* __restrict__ g,
                                                           float* __restrict__ out) {
    const int o = blockIdx.x * 256 + (threadIdx.x & 255);
    // force the wave-uniform half index into an SGPR so the xl4 addresses are
    // provably uniform (divergence analysis won't infer tid>>8 uniformity).
    const int half = __builtin_amdgcn_readfirstlane(threadIdx.x >> 8);
    const int b0 = blockIdx.y * 8 + half * 4;   // 4 rows per thread

    float aa[4], ss[4];
#pragma unroll
    for (int r = 0; r < 4; ++r) { aa[r] = 0.0f; ss[r] = 0.0f; }

#pragma unroll 4
    for (int i2 = 0; i2 < I_N / 2; ++i2) {
        const float w0  = w1[(2 * i2) * O_N + o];
        const float w1v = w1[(2 * i2 + 1) * O_N + o];
#pragma unroll
        for (int r = 0; r < 4; ++r) {
            const float4 q = xl4[(b0 + r) * (I_N / 2) + i2];  // (x_i, lx_i, x_{i+1}, lx_{i+1})
            aa[r] = fmaf(q.x, w0, aa[r]);
            ss[r] = fmaf(q.y, w0, ss[r]);
            aa[r] = fmaf(q.z, w1v, aa[r]);
            ss[r] = fmaf(q.w, w1v, ss[r]);
        }
    }

    const float g1 = 1.0f / (1.0f + expf(-g[o]));
    const float omg = 1.0f - g1;
#pragma unroll
    for (int r = 0; r < 4; ++r) {
        const float sv = ss[r];
        const float m1 = expf(fminf(sv, 20.0f));
        float msv = 1.0f;                       // fast path: m1 < 2e-35, term invisible
        if (sv > -80.0f) {                      // cold path (expected never): exact ms
            float p = 1.0f;
            const int b = b0 + r;
            for (int i = 0; i < I_N; ++i) {
                // ws_oi[o][i] = |w1.flat[o*I + i]|  (TF row-major reshape, I==O)
                const float wv = fabsf(w1[o * I_N + i]);
                const float xv = x[b * I_N + i];
                const float sg = (float)((xv > 0.0f) - (xv < 0.0f));  // sign(), 0 at 0
                p *= sg * wv + (1.0f - wv);
            }
            msv = fminf(fmaxf(p, -1.0f), 1.0f);
        }
        out[(b0 + r) * O_N + o] = g1 * aa[r] + omg * m1 * msv;
    }
}

extern "C" void kernel_launch(void* const* d_in, const int* in_sizes, int n_in,
                              void* d_out, int out_size, void* d_ws, size_t ws_size,
                              hipStream_t stream) {
    const float* x  = (const float*)d_in[0];   // [B, I]
    const float* wh = (const float*)d_in[1];   // [I, O]
    const float* mh = (const float*)d_in[2];   // [I, O]
    const float* g  = (const float*)d_in[3];   // [O]
    float* out = (float*)d_out;                // [B, O] fp32

    char* ws = (char*)d_ws;
    float*  w1 = (float*)ws;                   // 1 MB  [I,O]
    float2* xl = (float2*)(ws + (1u << 20));   // 4 MB  [B,I] packed (x, log|x|)

    const int prep_elems = I_N * O_N + B_N * I_N;          // 786432
    prep_kernel<<<prep_elems / 256, 256, 0, stream>>>(x, wh, mh, w1, xl);
    nalu_main_kernel<<<dim3(O_N / 256, B_N / 8), 512, 0, stream>>>(
        w1, (const float4*)xl, x, g, out);
}

// Round 3
// 73.888 us; speedup vs baseline: 2.8564x; 1.4734x over previous
//
#include <hip/hip_runtime.h>

// NALU B=1024, I=512, O=512 via fp16 MFMA.
//   w1 = tanh(w_hat)*sigmoid(m_hat)            [I,O]
//   a  = x @ w1 ; s = log(max(|x|,eps)) @ w1 ; m1 = exp(min(s,20))
//   out = g1*a + (1-g1)*m1*clip(ms,-1,1)
// s ~ N(-143, 11^2) for these inputs => m1 underflows to 0; ms term guarded
// exactly: any s > -80 takes a cold path computing the true sign-product.
//
// Structure: prep writes A (x and log|x|) and B (w1) as fp16 tiles pre-packed
// in mfma_f32_16x16x32_f16 fragment order => main kernel does NO LDS: each
// lane loads its 16B fragment straight from L2 (lane-contiguous) and MFMAs.
// Frag layouts (learn_hip-verified): A[m=lane&15][k=(lane>>4)*8+j],
// B[k=(lane>>4)*8+j][n=lane&15], D[m=(lane>>4)*4+reg][n=lane&15].

#define O_N 512
#define I_N 512

typedef _Float16 f16;
typedef _Float16 f16x8 __attribute__((ext_vector_type(8)));
typedef float f32x4 __attribute__((ext_vector_type(4)));

// ---- prep: pack A_x, A_l [64 mtiles][16 ktiles][64 lanes] f16x8,
//            B [32 ntiles][16 ktiles][64 lanes] f16x8, w1f fp32, g1 ----
__global__ __launch_bounds__(256) void prep_kernel(const float* __restrict__ x,
                                                   const float* __restrict__ wh,
                                                   const float* __restrict__ mh,
                                                   const float* __restrict__ g,
                                                   f16x8* __restrict__ apx,
                                                   f16x8* __restrict__ apl,
                                                   f16x8* __restrict__ bp,
                                                   float* __restrict__ w1f,
                                                   float* __restrict__ g1v) {
    const int blk = blockIdx.x;
    if (blk < 128) {                      // B-prep: 32768 threads, 8 w1 vals each
        const int t = blk * 256 + threadIdx.x;
        const int lane = t & 63;
        const int tk = (t >> 6) & 15;
        const int tn = t >> 10;           // 0..31
        const int n = tn * 16 + (lane & 15);
        const int k0 = tk * 32 + ((lane >> 4) & 3) * 8;
        f16x8 bf;
#pragma unroll
        for (int j = 0; j < 8; ++j) {
            const int k = k0 + j;
            const float w = tanhf(wh[k * O_N + n]) *
                            (1.0f / (1.0f + expf(-mh[k * O_N + n])));
            w1f[k * O_N + n] = w;         // fp32 copy for cold path
            bf[j] = (f16)w;
        }
        bp[t] = bf;                       // coalesced 16B/lane
    } else if (blk < 384) {               // A-prep: 65536 threads
        const int t = (blk - 128) * 256 + threadIdx.x;
        const int lane = t & 63;
        const int tk = (t >> 6) & 15;
        const int tm = t >> 10;           // 0..63
        const int m = tm * 16 + (lane & 15);
        const int k0 = tk * 32 + ((lane >> 4) & 3) * 8;
        const float4* x4 = (const float4*)(x + m * I_N + k0);
        const float4 q0 = x4[0], q1 = x4[1];
        const float vx[8] = {q0.x, q0.y, q0.z, q0.w, q1.x, q1.y, q1.z, q1.w};
        f16x8 fx, fl;
#pragma unroll
        for (int j = 0; j < 8; ++j) {
            fx[j] = (f16)vx[j];
            fl[j] = (f16)logf(fmaxf(fabsf(vx[j]), 1e-7f));
        }
        apx[t] = fx;
        apl[t] = fl;
    } else {                              // g-prep
        const int o = threadIdx.x;
        g1v[o]       = 1.0f / (1.0f + expf(-g[o]));
        g1v[o + 256] = 1.0f / (1.0f + expf(-g[o + 256]));
    }
}

// ---- main: grid (8, 32), 256 threads (4 waves). Block tile 32b x 64o.
// Wave (wm = w&1, wn = w>>1): rows b0..b0+15, cols o0..o0+31 (2 n-subtiles).
__global__ __launch_bounds__(256) void nalu_mfma_kernel(const f16x8* __restrict__ apx,
                                                        const f16x8* __restrict__ apl,
                                                        const f16x8* __restrict__ bp,
                                                        const float* __restrict__ g1v,
                                                        const float* __restrict__ w1f,
                                                        const float* __restrict__ x,
                                                        float* __restrict__ out) {
    const int lane = threadIdx.x & 63;
    const int w = threadIdx.x >> 6;
    const int b0 = blockIdx.y * 32 + (w & 1) * 16;
    const int o0 = blockIdx.x * 64 + (w >> 1) * 32;
    const int tm = b0 >> 4;
    const int tn0 = o0 >> 4;

    f32x4 ca0 = {0.f, 0.f, 0.f, 0.f}, ca1 = ca0, cs0 = ca0, cs1 = ca0;

    const f16x8* pax = apx + tm * (16 * 64) + lane;
    const f16x8* pal = apl + tm * (16 * 64) + lane;
    const f16x8* pb0 = bp + tn0 * (16 * 64) + lane;
    const f16x8* pb1 = bp + (tn0 + 1) * (16 * 64) + lane;

#pragma unroll 4
    for (int tk = 0; tk < 16; ++tk) {
        const f16x8 ax = pax[tk * 64];
        const f16x8 al = pal[tk * 64];
        const f16x8 bf0 = pb0[tk * 64];
        const f16x8 bf1 = pb1[tk * 64];
        ca0 = __builtin_amdgcn_mfma_f32_16x16x32_f16(ax, bf0, ca0, 0, 0, 0);
        ca1 = __builtin_amdgcn_mfma_f32_16x16x32_f16(ax, bf1, ca1, 0, 0, 0);
        cs0 = __builtin_amdgcn_mfma_f32_16x16x32_f16(al, bf0, cs0, 0, 0, 0);
        cs1 = __builtin_amdgcn_mfma_f32_16x16x32_f16(al, bf1, cs1, 0, 0, 0);
    }

    // epilogue: D[m=(lane>>4)*4+r][n=lane&15]
    const int col = lane & 15;
    const int rq = (lane >> 4) * 4;
#pragma unroll
    for (int t = 0; t < 2; ++t) {
        const int o = o0 + t * 16 + col;
        const float g1 = g1v[o];
        const float omg = 1.0f - g1;
        const f32x4 ca = t ? ca1 : ca0;
        const f32x4 cs = t ? cs1 : cs0;
#pragma unroll
        for (int r = 0; r < 4; ++r) {
            const int b = b0 + rq + r;
            const float sv = cs[r];
            const float m1 = expf(fminf(sv, 20.0f));
            float msv = 1.0f;
            if (sv > -80.0f) {            // cold path (expected never): exact ms
                float p = 1.0f;
                for (int i = 0; i < I_N; ++i) {
                    const float wv = fabsf(w1f[o * I_N + i]);  // |w1.flat[o*I+i]|
                    const float xv = x[b * I_N + i];
                    const float sg = (xv > 0.f) ? 1.f : ((xv < 0.f) ? -1.f : 0.f);
                    p *= sg * wv + (1.0f - wv);
                }
                msv = fminf(fmaxf(p, -1.0f), 1.0f);
            }
            out[b * O_N + o] = g1 * ca[r] + omg * m1 * msv;
        }
    }
}

extern "C" void kernel_launch(void* const* d_in, const int* in_sizes, int n_in,
                              void* d_out, int out_size, void* d_ws, size_t ws_size,
                              hipStream_t stream) {
    const float* x  = (const float*)d_in[0];   // [B, I]
    const float* wh = (const float*)d_in[1];   // [I, O]
    const float* mh = (const float*)d_in[2];   // [I, O]
    const float* g  = (const float*)d_in[3];   // [O]
    float* out = (float*)d_out;                // [B, O] fp32

    char* ws = (char*)d_ws;
    f16x8* apx = (f16x8*)ws;                          // 1 MB  (64*16*64 frags)
    f16x8* apl = (f16x8*)(ws + (1u << 20));           // 1 MB
    f16x8* bp  = (f16x8*)(ws + (2u << 20));           // 512 KB (32*16*64 frags)
    float* w1f = (float*)(ws + (5u << 19));           // 1 MB fp32 w1 (cold path)
    float* g1v = (float*)(ws + (7u << 19));           // 2 KB

    prep_kernel<<<385, 256, 0, stream>>>(x, wh, mh, g, apx, apl, bp, w1f, g1v);
    nalu_mfma_kernel<<<dim3(8, 32), 256, 0, stream>>>(apx, apl, bp, g1v, w1f, x, out);
}